// Round 2
// baseline (261.946 us; speedup 1.0000x reference)
//
#include <hip/hip_runtime.h>
#include <math.h>

namespace {
constexpr int Bn = 4, Rn = 16384, Sn = 128;
constexpr int NRAY = Bn * Rn;          // 65536 rays
constexpr int SI   = Sn - 1;           // 127 intervals
// Output layout: tuple concatenated flat in return order
constexpr size_t OFF_RGB   = 0;                                  // [B,R,3]
constexpr size_t OFF_DEPTH = OFF_RGB   + (size_t)NRAY * 3;       // [B,R,1]
constexpr size_t OFF_W     = OFF_DEPTH + (size_t)NRAY;           // [B,R,SI,1]
constexpr size_t OFF_WALL  = OFF_W     + (size_t)NRAY * SI;      // [B,R,SI,1]
constexpr size_t OFF_ALPHA = OFF_WALL  + (size_t)NRAY * SI;      // [B,R,SI,1]
constexpr size_t OFF_DMID  = OFF_ALPHA + (size_t)NRAY * SI;      // [B,R,SI,1]
constexpr float  EPSF  = 1e-10f;
constexpr float  LOG2E = 1.44269504088896340736f;
}

// DPP move helper: returns src shifted per ctrl; invalid/masked lanes get `oldv`.
template <int ctrl, int rmask>
__device__ __forceinline__ float dpp_mov(float x, float oldv) {
    return __int_as_float(__builtin_amdgcn_update_dpp(
        __float_as_int(oldv), __float_as_int(x), ctrl, rmask, 0xf, false));
}

// Wave64 inclusive prefix PRODUCT via DPP (LLVM AtomicOptimizer pattern).
__device__ __forceinline__ float scan_mul(float x) {
    x *= dpp_mov<0x111, 0xf>(x, 1.0f);  // row_shr:1
    x *= dpp_mov<0x112, 0xf>(x, 1.0f);  // row_shr:2
    x *= dpp_mov<0x114, 0xf>(x, 1.0f);  // row_shr:4
    x *= dpp_mov<0x118, 0xf>(x, 1.0f);  // row_shr:8
    x *= dpp_mov<0x142, 0xa>(x, 1.0f);  // row_bcast:15 -> rows 1,3
    x *= dpp_mov<0x143, 0xc>(x, 1.0f);  // row_bcast:31 -> rows 2,3
    return x;
}

// Wave64 inclusive prefix SUM via DPP; lane 63 ends with the wave total.
__device__ __forceinline__ float scan_add(float x) {
    x += dpp_mov<0x111, 0xf>(x, 0.0f);
    x += dpp_mov<0x112, 0xf>(x, 0.0f);
    x += dpp_mov<0x114, 0xf>(x, 0.0f);
    x += dpp_mov<0x118, 0xf>(x, 0.0f);
    x += dpp_mov<0x142, 0xa>(x, 0.0f);
    x += dpp_mov<0x143, 0xc>(x, 0.0f);
    return x;
}

// lane i gets lane i+1's value (wave_shl:1); lane 63 gets `oldv`.
__device__ __forceinline__ float next_lane(float x) {
    return dpp_mov<0x130, 0xf>(x, 0.0f);
}

// One wave (64 lanes) per ray; lane i owns intervals 2i and 2i+1.
__global__ __launch_bounds__(256) void raymarch_kernel(
    const float* __restrict__ colors,
    const float* __restrict__ dlog,
    const float* __restrict__ depths,
    float* __restrict__ out)
{
    const int gtid = blockIdx.x * 256 + threadIdx.x;
    const int ray  = gtid >> 6;
    const int lane = threadIdx.x & 63;

    const float2* dp = reinterpret_cast<const float2*>(depths) + (size_t)ray * (Sn / 2);
    const float2* gp = reinterpret_cast<const float2*>(dlog)   + (size_t)ray * (Sn / 2);
    const float2* cp = reinterpret_cast<const float2*>(colors) + (size_t)ray * (Sn * 3 / 2);

    float2 d  = dp[lane];          // depths: samples 2i, 2i+1
    float2 g  = gp[lane];          // density logits
    float2 c0 = cp[lane * 3 + 0];  // colors floats 6i..6i+5
    float2 c1 = cp[lane * 3 + 1];
    float2 c2 = cp[lane * 3 + 2];

    // sample 2i+2 from lane i+1 via DPP wave_shl:1 (no LDS)
    float d2  = next_lane(d.x);
    float g2  = next_lane(g.x);
    float cnx = next_lane(c0.x);
    float cny = next_lane(c0.y);
    float cnz = next_lane(c1.x);

    const bool valid1 = (lane < 63);   // interval 127 does not exist

    // interval j0 = 2i : samples (2i, 2i+1)
    float delta0 = d.y - d.x;
    float dm0    = 0.5f * (d.x + d.y);
    float x0     = 0.5f * (g.x + g.y) - 1.0f;
    float cm0x   = 0.5f * (c0.x + c1.y);
    float cm0y   = 0.5f * (c0.y + c2.x);
    float cm0z   = 0.5f * (c1.x + c2.y);

    // interval j1 = 2i+1 : samples (2i+1, 2i+2)
    float delta1 = valid1 ? (d2 - d.y)                 : 0.0f;
    float dm1    = valid1 ? 0.5f * (d.y + d2)          : 0.0f;
    float x1     = valid1 ? (0.5f * (g.y + g2) - 1.0f) : 0.0f;
    float cm1x   = valid1 ? 0.5f * (c1.y + cnx)        : 0.0f;
    float cm1y   = valid1 ? 0.5f * (c2.x + cny)        : 0.0f;
    float cm1z   = valid1 ? 0.5f * (c2.y + cnz)        : 0.0f;

    // softplus+alpha collapsed into base-2 HW transcendentals:
    //   l = log2(1 + exp2(x*log2e)) = softplus(x)/ln2 ;  alpha = 1 - exp2(-l*delta)
    float l0 = __log2f(1.0f + exp2f(x0 * LOG2E));
    float l1 = __log2f(1.0f + exp2f(x1 * LOG2E));
    float alpha0 = 1.0f - exp2f(-l0 * delta0);
    float alpha1 = 1.0f - exp2f(-l1 * delta1);   // 0 for lane 63 (delta1=0)
    float t0 = 1.0f - alpha0 + EPSF;
    float t1 = valid1 ? (1.0f - alpha1 + EPSF) : 1.0f;

    // cumprod: wave inclusive product scan of t0*t1, then exclusive via wave_shr:1
    float s  = scan_mul(t0 * t1);
    float T0 = dpp_mov<0x138, 0xf>(s, 1.0f);   // wave_shr:1; lane0 -> 1.0
    float T1 = T0 * t0;

    float w0 = (alpha0 + EPSF) * T0;
    float w1 = valid1 ? (alpha1 + EPSF) * T1 : 0.0f;

    // per-interval outputs (contiguous 127-float span per ray per array)
    size_t base = (size_t)ray * SI + 2 * lane;
    out[OFF_W     + base] = w0;
    out[OFF_WALL  + base] = w0;
    out[OFF_ALPHA + base] = alpha0;
    out[OFF_DMID  + base] = dm0;
    if (valid1) {
        out[OFF_W     + base + 1] = w1;
        out[OFF_WALL  + base + 1] = w1;
        out[OFF_ALPHA + base + 1] = alpha1;
        out[OFF_DMID  + base + 1] = dm1;
    }

    // composite reductions: sum-scans, totals land in lane 63
    float wsum = scan_add(w0 + w1);
    float rx   = scan_add(w0 * cm0x + w1 * cm1x);
    float ry   = scan_add(w0 * cm0y + w1 * cm1y);
    float rz   = scan_add(w0 * cm0z + w1 * cm1z);
    float dsum = scan_add(w0 * dm0 + w1 * dm1);

    if (lane == 63) {
        float cd = dsum / (EPSF + wsum);
        if (isnan(cd)) cd = 100.0f;               // nan_to_num(nan=MAX_DEPTH)
        cd = fminf(fmaxf(cd, 0.1f), 100.0f);      // clip; also maps +/-inf
        out[OFF_RGB + (size_t)ray * 3 + 0] = rx * 2.0f - 1.0f;
        out[OFF_RGB + (size_t)ray * 3 + 1] = ry * 2.0f - 1.0f;
        out[OFF_RGB + (size_t)ray * 3 + 2] = rz * 2.0f - 1.0f;
        out[OFF_DEPTH + ray] = cd;
    }
}

extern "C" void kernel_launch(void* const* d_in, const int* in_sizes, int n_in,
                              void* d_out, int out_size, void* d_ws, size_t ws_size,
                              hipStream_t stream) {
    const float* colors = (const float*)d_in[0];
    const float* dlog   = (const float*)d_in[1];
    const float* depths = (const float*)d_in[2];
    float* out = (float*)d_out;

    dim3 grid(NRAY / 4);   // 4 waves per 256-thread block, one ray per wave
    dim3 block(256);
    hipLaunchKernelGGL(raymarch_kernel, grid, block, 0, stream, colors, dlog, depths, out);
}